// Round 3
// baseline (426.046 us; speedup 1.0000x reference)
//
#include <hip/hip_runtime.h>
#include <hip/hip_bf16.h>
#include <math.h>

typedef __hip_bfloat16 bf16;

__device__ __forceinline__ float ldf(const void* p, int idx, bool isb) {
  if (isb) return __bfloat162float(((const bf16*)p)[idx]);
  return ((const float*)p)[idx];
}
__device__ __forceinline__ void stf(void* p, int idx, float v, bool isb) {
  if (isb) ((bf16*)p)[idx] = __float2bfloat16(v);
  else     ((float*)p)[idx] = v;
}

// ---------------------------------------------------------------------------
// Kernel 0: dtype detect. g_msa = ones(256). First 32-bit word:
//   f32  -> 0x3F800000 ; bf16 -> 0x3F803F80.
// ---------------------------------------------------------------------------
__global__ void k_detect(const unsigned int* __restrict__ w, int* __restrict__ flag) {
  if (threadIdx.x == 0 && blockIdx.x == 0)
    *flag = (w[0] == 0x3F803F80u) ? 1 : 0;
}

// ---------------------------------------------------------------------------
// Kernel 1: per-node pipeline (one wave per residue). LDS serial reductions.
// ---------------------------------------------------------------------------
__global__ __launch_bounds__(64) void k_node(
    const void* __restrict__ xyz, const void* __restrict__ state,
    const void* __restrict__ msa, const void* __restrict__ seq1hot,
    const void* __restrict__ g_msa, const void* __restrict__ b_msa,
    const void* __restrict__ g_state, const void* __restrict__ b_state,
    const void* __restrict__ g_node, const void* __restrict__ b_node,
    const void* __restrict__ Wx, const void* __restrict__ bx,
    const void* __restrict__ Wvv, const int* __restrict__ dflag,
    float* __restrict__ l0, float* __restrict__ CA, float* __restrict__ v,
    float* __restrict__ vproj, float* __restrict__ agg, float* __restrict__ v_agg)
{
  const bool isb = (*dflag != 0);
  const int i = blockIdx.x;
  const int lane = threadIdx.x;
  __shared__ float nin[312];
  __shared__ float red[64], red2[64];
  __shared__ float accrow[32];
  __shared__ float sxyz[9], sv9[9];

  // ---- msa LN (256) ----
  float x0 = ldf(msa, i * 256 + lane, isb);
  float x1 = ldf(msa, i * 256 + lane + 64, isb);
  float x2 = ldf(msa, i * 256 + lane + 128, isb);
  float x3 = ldf(msa, i * 256 + lane + 192, isb);
  red[lane]  = x0 + x1 + x2 + x3;
  red2[lane] = x0 * x0 + x1 * x1 + x2 * x2 + x3 * x3;
  if (lane < 9) sxyz[lane] = ldf(xyz, i * 9 + lane, isb);
  __syncthreads();
  float S = 0.f, Sq = 0.f;
  for (int t = 0; t < 64; ++t) { S += red[t]; Sq += red2[t]; }
  float mu  = S * (1.f / 256.f);
  float rs  = rsqrtf(fmaxf(Sq * (1.f / 256.f) - mu * mu, 0.f) + 1e-5f);
  nin[lane]       = (x0 - mu) * rs * ldf(g_msa, lane, isb)       + ldf(b_msa, lane, isb);
  nin[lane + 64]  = (x1 - mu) * rs * ldf(g_msa, lane + 64, isb)  + ldf(b_msa, lane + 64, isb);
  nin[lane + 128] = (x2 - mu) * rs * ldf(g_msa, lane + 128, isb) + ldf(b_msa, lane + 128, isb);
  nin[lane + 192] = (x3 - mu) * rs * ldf(g_msa, lane + 192, isb) + ldf(b_msa, lane + 192, isb);
  if (lane < 21) nin[256 + lane] = ldf(seq1hot, i * 21 + lane, isb);
  if (lane < 3)  nin[309 + lane] = 0.f;

  // ---- state LN (32) ----
  float sx = (lane < 32) ? ldf(state, i * 32 + lane, isb) : 0.f;
  __syncthreads();                 // everyone done reading red/red2 above
  red[lane]  = sx;
  red2[lane] = sx * sx;
  __syncthreads();
  float Ss = 0.f, Ssq = 0.f;
  for (int t = 0; t < 32; ++t) { Ss += red[t]; Ssq += red2[t]; }
  float mus = Ss * (1.f / 32.f);
  float rss = rsqrtf(fmaxf(Ssq * (1.f / 32.f) - mus * mus, 0.f) + 1e-5f);
  if (lane < 32) nin[277 + lane] = (sx - mus) * rss * ldf(g_state, lane, isb) + ldf(b_state, lane, isb);
  __syncthreads();

  // ---- l0 = LN(node @ Wx + bx): one lane per output column ----
  if (lane < 32) {
    float acc = ldf(bx, lane, isb);
    for (int f = 0; f < 309; ++f) acc += nin[f] * ldf(Wx, f * 32 + lane, isb);
    accrow[lane] = acc;
  }
  __syncthreads();
  float Sa = 0.f, Saq = 0.f;
  for (int t = 0; t < 32; ++t) { float a = accrow[t]; Sa += a; Saq += a * a; }
  float mn = Sa * (1.f / 32.f);
  float rn = rsqrtf(fmaxf(Saq * (1.f / 32.f) - mn * mn, 0.f) + 1e-5f);
  if (lane < 32)
    l0[i * 32 + lane] = (accrow[lane] - mn) * rn * ldf(g_node, lane, isb) + ldf(b_node, lane, isb);

  // ---- geometry + zero-init accumulators ----
  if (lane < 3) CA[i * 3 + lane] = sxyz[3 + lane];
  if (lane < 9) {
    float vv = sxyz[lane] - sxyz[3 + lane % 3];
    v[i * 9 + lane] = vv;
    sv9[lane] = vv;
  }
  if (lane < 32) agg[i * 32 + lane] = 0.f;
  if (lane < 9)  v_agg[i * 9 + lane] = 0.f;
  __syncthreads();
  if (lane < 9) {
    int o = lane / 3, xc = lane % 3;
    float s = 0.f;
    for (int ii = 0; ii < 3; ++ii) s += ldf(Wvv, ii * 3 + o, isb) * sv9[ii * 3 + xc];
    vproj[i * 9 + lane] = s;
  }
}

// ---------------------------------------------------------------------------
// Kernel 2: top-64 nearest neighbors per residue (bitonic sort of 512 keys).
// ---------------------------------------------------------------------------
__global__ __launch_bounds__(256) void k_topk(
    const float* __restrict__ CA, int* __restrict__ nbr)
{
  __shared__ float cx[512], cy[512], cz[512];
  __shared__ unsigned long long key[512];
  const int i = blockIdx.x;
  for (int t = threadIdx.x; t < 512; t += 256) {
    cx[t] = CA[t * 3 + 0];
    cy[t] = CA[t * 3 + 1];
    cz[t] = CA[t * 3 + 2];
  }
  __syncthreads();
  float xi = cx[i], yi = cy[i], zi = cz[i];
  for (int t = threadIdx.x; t < 512; t += 256) {
    float dx = cx[t] - xi, dy = cy[t] - yi, dz = cz[t] - zi;
    float d2 = dx * dx + dy * dy + dz * dz;
    unsigned int bits = (t == i) ? 0x7f800000u : __float_as_uint(d2);  // diag -> +inf
    key[t] = ((unsigned long long)bits << 32) | (unsigned int)t;
  }
  for (int k = 2; k <= 512; k <<= 1) {
    for (int j = k >> 1; j > 0; j >>= 1) {
      __syncthreads();
      int t  = threadIdx.x;
      int i0 = ((t & ~(j - 1)) << 1) | (t & (j - 1));
      int i1 = i0 | j;
      bool up = ((i0 & k) == 0);
      unsigned long long a = key[i0], b = key[i1];
      if ((a > b) == up) { key[i0] = b; key[i1] = a; }
    }
  }
  __syncthreads();
  if (threadIdx.x < 64)
    nbr[i * 64 + threadIdx.x] = (int)(key[threadIdx.x] & 0xffffffffu);
}

// ---------------------------------------------------------------------------
// Kernel 3: per-edge messages + scatter. One block per src residue i; 4 waves,
// each wave handles 16 edges. Block-uniform syncs.
// ---------------------------------------------------------------------------
__global__ __launch_bounds__(256) void k_edge(
    const void* __restrict__ pair,
    const void* __restrict__ g_pair, const void* __restrict__ b_pair,
    const void* __restrict__ We1, const void* __restrict__ be1,
    const void* __restrict__ g_e1, const void* __restrict__ b_e1,
    const void* __restrict__ W1, const void* __restrict__ b1,
    const void* __restrict__ Wv, const int* __restrict__ dflag,
    const int* __restrict__ nbr,
    const float* __restrict__ l0, const float* __restrict__ CA,
    const float* __restrict__ v, const float* __restrict__ vproj,
    float* __restrict__ agg, float* __restrict__ v_agg)
{
  const bool isb = (*dflag != 0);
  __shared__ float sWe1[128 * 32];
  __shared__ float sW1[100 * 32];
  __shared__ float sWv[192];
  __shared__ float sgp[128], sbp[128];
  __shared__ float sbe1[32], sge1[32], sbee[32], sb1[32];
  __shared__ float sl0i[32], sCAi[3], svi[9], svpi[9];
  __shared__ float ped[4][128];
  __shared__ float erow[4][32];
  __shared__ float mrow[4][32];
  __shared__ float sinv[4][100];

  const int i = blockIdx.x;
  const int tid = threadIdx.x;
  for (int t = tid; t < 128 * 32; t += 256) sWe1[t] = ldf(We1, t, isb);
  for (int t = tid; t < 100 * 32; t += 256) sW1[t]  = ldf(W1, t, isb);
  if (tid < 192) sWv[tid] = ldf(Wv, tid, isb);
  if (tid < 128) { sgp[tid] = ldf(g_pair, tid, isb); sbp[tid] = ldf(b_pair, tid, isb); }
  if (tid >= 128 && tid < 160) {
    int c = tid - 128;
    sbe1[c] = ldf(be1, c, isb); sge1[c] = ldf(g_e1, c, isb);
    sbee[c] = ldf(b_e1, c, isb); sb1[c] = ldf(b1, c, isb);
  }
  if (tid >= 224) sl0i[tid - 224] = l0[i * 32 + (tid - 224)];
  if (tid < 3) sCAi[tid] = CA[i * 3 + tid];
  if (tid >= 64 && tid < 73)  svi[tid - 64]  = v[i * 9 + (tid - 64)];
  if (tid >= 96 && tid < 105) svpi[tid - 96] = vproj[i * 9 + (tid - 96)];
  __syncthreads();

  const int w = tid >> 6, lane = tid & 63;

  for (int step = 0; step < 16; ++step) {
    const int kk = step * 4 + w;
    const int j = nbr[i * 64 + kk];
    const size_t pbase = ((size_t)(i * 512 + j)) * 128;

    // stage raw pair row
    ped[w][2 * lane]     = ldf(pair, pbase + 2 * lane, isb);
    ped[w][2 * lane + 1] = ldf(pair, pbase + 2 * lane + 1, isb);
    __syncthreads();  // S1

    // pair-row LN stats (serial, identical on all lanes)
    float S = 0.f, Sq = 0.f;
    for (int f = 0; f < 128; ++f) { float p = ped[w][f]; S += p; Sq += p * p; }
    float mu = S * (1.f / 128.f);
    float rs = rsqrtf(fmaxf(Sq * (1.f / 128.f) - mu * mu, 0.f) + 1e-5f);

    // e1 pre-LN GEMV: lane c computes full 128-dot, normalizing on the fly
    if (lane < 32) {
      float acc = sbe1[lane];
      for (int f = 0; f < 128; ++f) {
        float pe = (ped[w][f] - mu) * rs * sgp[f] + sbp[f];
        acc += pe * sWe1[f * 32 + lane];
      }
      erow[w][lane] = acc;
    }
    __syncthreads();  // S2

    float Se = 0.f, Seq = 0.f;
    for (int t = 0; t < 32; ++t) { float a = erow[w][t]; Se += a; Seq += a * a; }
    float m2 = Se * (1.f / 32.f);
    float r2 = rsqrtf(fmaxf(Seq * (1.f / 32.f) - m2 * m2, 0.f) + 1e-5f);

    // geometry (every lane, identical values)
    float dex = CA[j * 3 + 0] - sCAi[0];
    float dey = CA[j * 3 + 1] - sCAi[1];
    float dez = CA[j * 3 + 2] - sCAi[2];
    float dn  = sqrtf(dex * dex + dey * dey + dez * dez);
    float idn = 1.f / (dn + 1e-8f);
    float dux = dex * idn, duy = dey * idn, duz = dez * idn;

    // build inv[100]
    if (lane < 32) {
      sinv[w][lane]      = sl0i[lane];
      sinv[w][32 + lane] = l0[j * 32 + lane];
      sinv[w][64 + lane] = (erow[w][lane] - m2) * r2 * sge1[lane] + sbee[lane];
    }
    if (lane == 0) {
      sinv[w][96] = dn;
      sinv[w][97] = svi[0] * dux + svi[1] * duy + svi[2] * duz;
      sinv[w][98] = svi[3] * dux + svi[4] * duy + svi[5] * duz;
      sinv[w][99] = svi[6] * dux + svi[7] * duy + svi[8] * duz;
    }
    __syncthreads();  // S3

    // m = gelu(inv @ W1 + b1); scatter to agg
    if (lane < 32) {
      float a1 = sb1[lane];
      for (int f = 0; f < 100; ++f) a1 += sinv[w][f] * sW1[f * 32 + lane];
      float u  = 0.7978845608028654f * (a1 + 0.044715f * a1 * a1 * a1);
      float mm = 0.5f * a1 * (1.f + tanhf(u));   // jax.nn.gelu approximate=True
      mrow[w][lane] = mm;
      atomicAdd(&agg[j * 32 + lane], mm);
    }
    __syncthreads();  // S4

    // coef = m @ Wv; scatter vmsg to v_agg
    if (lane < 9) {
      int o = lane / 3, xx = lane % 3;
      float cd = 0.f, cv = 0.f;
      for (int c = 0; c < 32; ++c) {
        float m = mrow[w][c];
        cd += m * sWv[c * 6 + o];
        cv += m * sWv[c * 6 + 3 + o];
      }
      float dcomp = (xx == 0) ? dex : ((xx == 1) ? dey : dez);
      atomicAdd(&v_agg[j * 9 + lane], cd * dcomp + cv * svpi[o * 3 + xx]);
    }
    __syncthreads();  // S5
  }
}

// ---------------------------------------------------------------------------
// Kernel 4: output heads. grid 512, block 64.
// ---------------------------------------------------------------------------
__global__ __launch_bounds__(64) void k_out(
    const float* __restrict__ l0, const float* __restrict__ agg,
    const float* __restrict__ v, const float* __restrict__ v_agg,
    const float* __restrict__ CA,
    const void* __restrict__ W2, const void* __restrict__ b2,
    const void* __restrict__ Wself,
    const void* __restrict__ g_state, const void* __restrict__ b_state,
    const void* __restrict__ Wl, const void* __restrict__ bl,
    const int* __restrict__ dflag, void* __restrict__ out)
{
  const bool isb = (*dflag != 0);
  const int l = blockIdx.x;
  const int lane = threadIdx.x;
  __shared__ float scat[64], hrow[32], hwl[32], soff[9];
  if (lane < 32) { scat[lane] = l0[l * 32 + lane]; scat[32 + lane] = agg[l * 32 + lane]; }
  __syncthreads();

  // h_out = [l0, agg] @ W2 + b2 (one lane per column)
  if (lane < 32) {
    float acc = ldf(b2, lane, isb);
    for (int f = 0; f < 64; ++f) acc += scat[f] * ldf(W2, f * 32 + lane, isb);
    hrow[lane] = acc;
  }
  __syncthreads();

  float Sh = 0.f, Shq = 0.f;
  for (int t = 0; t < 32; ++t) { float a = hrow[t]; Sh += a; Shq += a * a; }
  float mu = Sh * (1.f / 32.f);
  float rs = rsqrtf(fmaxf(Shq * (1.f / 32.f) - mu * mu, 0.f) + 1e-5f);
  if (lane < 32) {
    float hn = (hrow[lane] - mu) * rs * ldf(g_state, lane, isb) + ldf(b_state, lane, isb);
    hwl[lane] = hn * ldf(Wl, lane, isb);
  }
  // v_out = Wself^T v + v_agg
  if (lane < 9) {
    int o = lane / 3, xx = lane % 3;
    float s = v_agg[l * 9 + lane];
    for (int ii = 0; ii < 3; ++ii) s += ldf(Wself, ii * 3 + o, isb) * v[l * 9 + ii * 3 + xx];
    soff[lane] = s;
  }
  __syncthreads();

  if (lane == 0) {
    float pre = ldf(bl, 0, isb);
    for (int t = 0; t < 32; ++t) pre += hwl[t];
    stf(out, 4608 + l, 1.f / (1.f + expf(-pre)), isb);
  }
  if (lane < 9) {
    int xx = lane % 3;
    float add = (l == 0) ? 0.f : (CA[l * 3 + xx] + soff[3 + xx]);  // residue 0 zeroed
    stf(out, l * 9 + lane, soff[lane] + add, isb);
  }
}

extern "C" void kernel_launch(void* const* d_in, const int* in_sizes, int n_in,
                              void* d_out, int out_size, void* d_ws, size_t ws_size,
                              hipStream_t stream) {
  (void)in_sizes; (void)n_in; (void)out_size; (void)ws_size;
  const void* xyz     = d_in[0];
  const void* state   = d_in[1];
  const void* msa     = d_in[4];
  const void* pair    = d_in[5];
  const void* seq1hot = d_in[6];
  const void* g_msa   = d_in[10];
  const void* b_msa   = d_in[11];
  const void* g_pair  = d_in[12];
  const void* b_pair  = d_in[13];
  const void* g_state = d_in[14];
  const void* b_state = d_in[15];
  const void* g_node  = d_in[16];
  const void* b_node  = d_in[17];
  const void* g_e1    = d_in[18];
  const void* b_e1    = d_in[19];
  const void* Wx      = d_in[20];
  const void* bx      = d_in[21];
  const void* We1     = d_in[22];
  const void* be1     = d_in[23];
  const void* W1      = d_in[24];
  const void* b1      = d_in[25];
  const void* W2      = d_in[26];
  const void* b2      = d_in[27];
  const void* Wv      = d_in[28];
  const void* Wvv     = d_in[29];
  const void* Wself   = d_in[30];
  const void* Wl      = d_in[31];
  const void* bl      = d_in[32];

  float* ws    = (float*)d_ws;
  float* l0    = ws;            // 512*32
  float* CA    = ws + 16384;    // 512*3
  float* v     = ws + 17920;    // 512*9
  float* vproj = ws + 22528;    // 512*9
  float* agg   = ws + 27136;    // 512*32
  float* v_agg = ws + 43520;    // 512*9
  int*   nbr   = (int*)(ws + 48128);  // 512*64 ints -> float slots 48128..80895
  int*   dflag = (int*)(ws + 80896);

  hipLaunchKernelGGL(k_detect, dim3(1), dim3(64), 0, stream,
                     (const unsigned int*)g_msa, dflag);
  hipLaunchKernelGGL(k_node, dim3(512), dim3(64), 0, stream,
                     xyz, state, msa, seq1hot, g_msa, b_msa, g_state, b_state,
                     g_node, b_node, Wx, bx, Wvv, dflag, l0, CA, v, vproj, agg, v_agg);
  hipLaunchKernelGGL(k_topk, dim3(512), dim3(256), 0, stream, CA, nbr);
  hipLaunchKernelGGL(k_edge, dim3(512), dim3(256), 0, stream,
                     pair, g_pair, b_pair, We1, be1, g_e1, b_e1, W1, b1, Wv, dflag,
                     nbr, l0, CA, v, vproj, agg, v_agg);
  hipLaunchKernelGGL(k_out, dim3(512), dim3(64), 0, stream,
                     l0, agg, v, v_agg, CA, W2, b2, Wself, g_state, b_state, Wl, bl,
                     dflag, (void*)d_out);
}

// Round 4
// 326.371 us; speedup vs baseline: 1.3054x; 1.3054x over previous
//
#include <hip/hip_runtime.h>
#include <hip/hip_bf16.h>
#include <math.h>

typedef __hip_bfloat16 bf16;

__device__ __forceinline__ float ldf(const void* p, long idx, bool isb) {
  if (isb) return __bfloat162float(((const bf16*)p)[idx]);
  return ((const float*)p)[idx];
}
__device__ __forceinline__ void stf(void* p, long idx, float v, bool isb) {
  if (isb) ((bf16*)p)[idx] = __float2bfloat16(v);
  else     ((float*)p)[idx] = v;
}
// butterfly sum across the full 64-lane wave
__device__ __forceinline__ float wsum64(float x) {
#pragma unroll
  for (int off = 32; off > 0; off >>= 1) x += __shfl_xor(x, off, 64);
  return x;
}

// ---------------------------------------------------------------------------
// Kernel 0: dtype detect. g_msa = ones(256). First word: f32 -> 0x3F800000,
// bf16 -> 0x3F803F80.  (Round 3 established f32, but keep the guard.)
// ---------------------------------------------------------------------------
__global__ void k_detect(const unsigned int* __restrict__ w, int* __restrict__ flag) {
  if (threadIdx.x == 0 && blockIdx.x == 0)
    *flag = (w[0] == 0x3F803F80u) ? 1 : 0;
}

// ---------------------------------------------------------------------------
// Kernel 1: per-node pipeline. 256 threads per residue, shuffle+LDS reductions.
// ---------------------------------------------------------------------------
__global__ __launch_bounds__(256) void k_node(
    const void* __restrict__ xyz, const void* __restrict__ state,
    const void* __restrict__ msa, const void* __restrict__ seq1hot,
    const void* __restrict__ g_msa, const void* __restrict__ b_msa,
    const void* __restrict__ g_state, const void* __restrict__ b_state,
    const void* __restrict__ g_node, const void* __restrict__ b_node,
    const void* __restrict__ Wx, const void* __restrict__ bx,
    const void* __restrict__ Wvv, const int* __restrict__ dflag,
    float* __restrict__ l0, float* __restrict__ CA, float* __restrict__ v,
    float* __restrict__ vproj, float* __restrict__ agg, float* __restrict__ v_agg)
{
  const bool isb = (*dflag != 0);
  const int i = blockIdx.x;
  const int t = threadIdx.x;
  const int lane = t & 63, w = t >> 6;
  __shared__ float nin[312];
  __shared__ float wred[2][4];
  __shared__ float part[8][32];
  __shared__ float sxyz[9], sv9[9];

  // ---- msa LN (256): one element per thread ----
  float x = ldf(msa, i * 256 + t, isb);
  float s1 = wsum64(x), s2 = wsum64(x * x);
  if (lane == 0) { wred[0][w] = s1; wred[1][w] = s2; }
  if (t < 9) sxyz[t] = ldf(xyz, i * 9 + t, isb);
  __syncthreads();
  float S  = wred[0][0] + wred[0][1] + wred[0][2] + wred[0][3];
  float Sq = wred[1][0] + wred[1][1] + wred[1][2] + wred[1][3];
  float mu = S * (1.f / 256.f);
  float rs = rsqrtf(fmaxf(Sq * (1.f / 256.f) - mu * mu, 0.f) + 1e-5f);
  nin[t] = (x - mu) * rs * ldf(g_msa, t, isb) + ldf(b_msa, t, isb);
  if (t < 21) nin[256 + t] = ldf(seq1hot, i * 21 + t, isb);
  if (t < 3)  nin[309 + t] = 0.f;

  // ---- state LN (32): wave 0 only ----
  if (w == 0) {
    float sx  = (lane < 32) ? ldf(state, i * 32 + lane, isb) : 0.f;
    float Ss  = wsum64(sx), Ssq = wsum64(sx * sx);
    float mus = Ss * (1.f / 32.f);
    float rss = rsqrtf(fmaxf(Ssq * (1.f / 32.f) - mus * mus, 0.f) + 1e-5f);
    if (lane < 32)
      nin[277 + lane] = (sx - mus) * rss * ldf(g_state, lane, isb) + ldf(b_state, lane, isb);
  }
  __syncthreads();

  // ---- Wx GEMV: thread (c, g) handles rows f ≡ g (mod 8) ----
  const int c = t & 31, g = t >> 5;
  float acc = 0.f;
  for (int f = g; f < 309; f += 8) acc += nin[f] * ldf(Wx, f * 32 + c, isb);
  part[g][c] = acc;
  __syncthreads();

  if (w == 0) {
    float a = 0.f;
    if (lane < 32) {
      a = ldf(bx, lane, isb);
#pragma unroll
      for (int gg = 0; gg < 8; ++gg) a += part[gg][lane];
    }
    float Sa = wsum64(a), Saq = wsum64(a * a);   // lanes >=32 contribute 0
    float mn = Sa * (1.f / 32.f);
    float rn = rsqrtf(fmaxf(Saq * (1.f / 32.f) - mn * mn, 0.f) + 1e-5f);
    if (lane < 32)
      l0[i * 32 + lane] = (a - mn) * rn * ldf(g_node, lane, isb) + ldf(b_node, lane, isb);
  } else if (w == 1) {
    if (lane < 3) CA[i * 3 + lane] = sxyz[3 + lane];
    if (lane < 9) {
      float vv = sxyz[lane] - sxyz[3 + lane % 3];
      v[i * 9 + lane] = vv;
      sv9[lane] = vv;
    }
    if (lane < 32) agg[i * 32 + lane] = 0.f;
  } else if (w == 2) {
    if (lane < 9) v_agg[i * 9 + lane] = 0.f;
  }
  __syncthreads();
  if (w == 1 && lane < 9) {
    int o = lane / 3, xc = lane % 3;
    float s = 0.f;
#pragma unroll
    for (int ii = 0; ii < 3; ++ii) s += ldf(Wvv, ii * 3 + o, isb) * sv9[ii * 3 + xc];
    vproj[i * 9 + lane] = s;
  }
}

// ---------------------------------------------------------------------------
// Kernel 2: top-64 NN per residue (bitonic sort of 512 packed keys).
// ---------------------------------------------------------------------------
__global__ __launch_bounds__(256) void k_topk(
    const float* __restrict__ CA, int* __restrict__ nbr)
{
  __shared__ float cx[512], cy[512], cz[512];
  __shared__ unsigned long long key[512];
  const int i = blockIdx.x;
  for (int t = threadIdx.x; t < 512; t += 256) {
    cx[t] = CA[t * 3 + 0];
    cy[t] = CA[t * 3 + 1];
    cz[t] = CA[t * 3 + 2];
  }
  __syncthreads();
  float xi = cx[i], yi = cy[i], zi = cz[i];
  for (int t = threadIdx.x; t < 512; t += 256) {
    float dx = cx[t] - xi, dy = cy[t] - yi, dz = cz[t] - zi;
    float d2 = dx * dx + dy * dy + dz * dz;
    unsigned int bits = (t == i) ? 0x7f800000u : __float_as_uint(d2);  // diag -> +inf
    key[t] = ((unsigned long long)bits << 32) | (unsigned int)t;
  }
  for (int k = 2; k <= 512; k <<= 1) {
    for (int j = k >> 1; j > 0; j >>= 1) {
      __syncthreads();
      int t  = threadIdx.x;
      int i0 = ((t & ~(j - 1)) << 1) | (t & (j - 1));
      int i1 = i0 | j;
      bool up = ((i0 & k) == 0);
      unsigned long long a = key[i0], b = key[i1];
      if ((a > b) == up) { key[i0] = b; key[i1] = a; }
    }
  }
  __syncthreads();
  if (threadIdx.x < 64)
    nbr[i * 64 + threadIdx.x] = (int)(key[threadIdx.x] & 0xffffffffu);
}

// ---------------------------------------------------------------------------
// Kernel 3: per-edge messages + scatter. 1024 blocks: (src i, half); 4 waves,
// one wave per edge, 8 edges per wave. Shuffle reductions; 2 barriers/step.
// ---------------------------------------------------------------------------
__global__ __launch_bounds__(256) void k_edge(
    const void* __restrict__ pair,
    const void* __restrict__ g_pair, const void* __restrict__ b_pair,
    const void* __restrict__ We1, const void* __restrict__ be1,
    const void* __restrict__ g_e1, const void* __restrict__ b_e1,
    const void* __restrict__ W1, const void* __restrict__ b1,
    const void* __restrict__ Wv, const int* __restrict__ dflag,
    const int* __restrict__ nbr,
    const float* __restrict__ l0, const float* __restrict__ CA,
    const float* __restrict__ v, const float* __restrict__ vproj,
    float* __restrict__ agg, float* __restrict__ v_agg)
{
  const bool isb = (*dflag != 0);
  __shared__ float sWe1[128 * 32];
  __shared__ float sW1[100 * 32];
  __shared__ float sWv[192];
  __shared__ float sgp[128], sbp[128];
  __shared__ float sbe1[32], sge1[32], sbee[32], sb1[32];
  __shared__ float sl0i[32], sCAi[3], svi[9], svpi[9];
  __shared__ float ped[4][128];
  __shared__ float sinv[4][100];

  const int i    = blockIdx.x >> 1;
  const int half = blockIdx.x & 1;
  const int tid  = threadIdx.x;
  for (int t = tid; t < 128 * 32; t += 256) sWe1[t] = ldf(We1, t, isb);
  for (int t = tid; t < 100 * 32; t += 256) sW1[t]  = ldf(W1, t, isb);
  if (tid < 192) sWv[tid] = ldf(Wv, tid, isb);
  if (tid < 128) { sgp[tid] = ldf(g_pair, tid, isb); sbp[tid] = ldf(b_pair, tid, isb); }
  if (tid >= 128 && tid < 160) {
    int cc = tid - 128;
    sbe1[cc] = ldf(be1, cc, isb); sge1[cc] = ldf(g_e1, cc, isb);
    sbee[cc] = ldf(b_e1, cc, isb); sb1[cc] = ldf(b1, cc, isb);
  }
  if (tid >= 224) sl0i[tid - 224] = l0[i * 32 + (tid - 224)];
  if (tid < 3) sCAi[tid] = CA[i * 3 + tid];
  if (tid >= 64 && tid < 73)  svi[tid - 64]  = v[i * 9 + (tid - 64)];
  if (tid >= 96 && tid < 105) svpi[tid - 96] = vproj[i * 9 + (tid - 96)];
  __syncthreads();

  const int w = tid >> 6, lane = tid & 63;
  const int c = lane & 31, h = lane >> 5;

  // constant part of inv (l0[i]) — written once, read after >=2 barriers
  if (h == 0) sinv[w][c] = sl0i[c];

  for (int step = 0; step < 8; ++step) {
    const int kk = half * 32 + step * 4 + w;
    const int j  = nbr[i * 64 + kk];
    const size_t pbase = ((size_t)(i * 512 + j)) * 128;

    // pair row: 2 consecutive elements per lane
    float p0, p1;
    if (isb) {
      p0 = __bfloat162float(((const bf16*)pair)[pbase + 2 * lane]);
      p1 = __bfloat162float(((const bf16*)pair)[pbase + 2 * lane + 1]);
    } else {
      float2 pp = ((const float2*)pair)[(pbase >> 1) + lane];
      p0 = pp.x; p1 = pp.y;
    }
    float lj = 0.f;
    if (h == 0) lj = l0[j * 32 + c];
    float cax = CA[j * 3 + 0], cay = CA[j * 3 + 1], caz = CA[j * 3 + 2];

    float S  = wsum64(p0 + p1);
    float Sq = wsum64(p0 * p0 + p1 * p1);
    float mu = S * (1.f / 128.f);
    float rs = rsqrtf(fmaxf(Sq * (1.f / 128.f) - mu * mu, 0.f) + 1e-5f);
    ped[w][2 * lane]     = (p0 - mu) * rs * sgp[2 * lane]     + sbp[2 * lane];
    ped[w][2 * lane + 1] = (p1 - mu) * rs * sgp[2 * lane + 1] + sbp[2 * lane + 1];
    __syncthreads();  // S1: ped ready

    // e1 = LN(pe @ We1 + be1): lane (c,h), inner half each
    float acc = 0.f;
    {
      const float* pw = ped[w];
      const int fb = h * 64;
#pragma unroll 8
      for (int f = 0; f < 64; ++f) acc += pw[fb + f] * sWe1[(fb + f) * 32 + c];
    }
    acc += __shfl_xor(acc, 32, 64);
    acc += sbe1[c];
    float m2 = wsum64(acc) * (1.f / 64.f);                       // halves duplicated
    float r2 = rsqrtf(fmaxf(wsum64(acc * acc) * (1.f / 64.f) - m2 * m2, 0.f) + 1e-5f);
    float we = (acc - m2) * r2 * sge1[c] + sbee[c];

    // geometry (all lanes)
    float dex = cax - sCAi[0], dey = cay - sCAi[1], dez = caz - sCAi[2];
    float dn  = sqrtf(dex * dex + dey * dey + dez * dez);
    float idn = 1.f / (dn + 1e-8f);
    float dux = dex * idn, duy = dey * idn, duz = dez * idn;

    if (h == 0) { sinv[w][32 + c] = lj; sinv[w][64 + c] = we; }
    if (lane == 0) {
      sinv[w][96] = dn;
      sinv[w][97] = svi[0] * dux + svi[1] * duy + svi[2] * duz;
      sinv[w][98] = svi[3] * dux + svi[4] * duy + svi[5] * duz;
      sinv[w][99] = svi[6] * dux + svi[7] * duy + svi[8] * duz;
    }
    __syncthreads();  // S2: sinv ready

    // m = gelu(inv @ W1 + b1)
    float a1 = 0.f;
    {
      const float* iv = sinv[w];
      const int fb = h * 50;
#pragma unroll 5
      for (int f = 0; f < 50; ++f) a1 += iv[fb + f] * sW1[(fb + f) * 32 + c];
    }
    a1 += __shfl_xor(a1, 32, 64);
    a1 += sb1[c];
    float u  = 0.7978845608028654f * (a1 + 0.044715f * a1 * a1 * a1);
    float mm = 0.5f * a1 * (1.f + tanhf(u));   // jax.nn.gelu approximate=True

    if (h == 0) atomicAdd(&agg[j * 32 + c], mm);

    // coef = m @ Wv (6 butterfly sums; halves duplicated -> x0.5)
    float co[6];
#pragma unroll
    for (int o = 0; o < 6; ++o) co[o] = 0.5f * wsum64(mm * sWv[c * 6 + o]);
    if (lane < 9) {
      int o = lane / 3, xx = lane % 3;
      float dcomp = (xx == 0) ? dex : ((xx == 1) ? dey : dez);
      atomicAdd(&v_agg[j * 9 + lane], co[o] * dcomp + co[3 + o] * svpi[o * 3 + xx]);
    }
    // next step's ped/sinv writes are ordered by the next S1/S2 barriers
  }
}

// ---------------------------------------------------------------------------
// Kernel 4: output heads. grid 512, block 64, shuffle reductions.
// ---------------------------------------------------------------------------
__global__ __launch_bounds__(64) void k_out(
    const float* __restrict__ l0, const float* __restrict__ agg,
    const float* __restrict__ v, const float* __restrict__ v_agg,
    const float* __restrict__ CA,
    const void* __restrict__ W2, const void* __restrict__ b2,
    const void* __restrict__ Wself,
    const void* __restrict__ g_state, const void* __restrict__ b_state,
    const void* __restrict__ Wl, const void* __restrict__ bl,
    const int* __restrict__ dflag, void* __restrict__ out)
{
  const bool isb = (*dflag != 0);
  const int l = blockIdx.x;
  const int lane = threadIdx.x;
  const int c = lane & 31, h = lane >> 5;
  __shared__ float scat[64], soff[9];
  if (lane < 32) { scat[lane] = l0[l * 32 + lane]; scat[32 + lane] = agg[l * 32 + lane]; }
  __syncthreads();

  // h_out = [l0, agg] @ W2 + b2 : lane (c,h), inner half each
  float acc = 0.f;
  {
    const int fb = h * 32;
    for (int f = 0; f < 32; ++f) acc += scat[fb + f] * ldf(W2, (fb + f) * 32 + c, isb);
  }
  acc += __shfl_xor(acc, 32, 64);
  acc += ldf(b2, c, isb);

  float mu = wsum64(acc) * (1.f / 64.f);
  float rs = rsqrtf(fmaxf(wsum64(acc * acc) * (1.f / 64.f) - mu * mu, 0.f) + 1e-5f);
  float hn = (acc - mu) * rs * ldf(g_state, c, isb) + ldf(b_state, c, isb);
  float pre = 0.5f * wsum64(hn * ldf(Wl, c, isb)) + ldf(bl, 0, isb);
  if (lane == 0) stf(out, 4608 + l, 1.f / (1.f + expf(-pre)), isb);

  if (lane < 9) {
    int o = lane / 3, xx = lane % 3;
    float s = v_agg[l * 9 + lane];
#pragma unroll
    for (int ii = 0; ii < 3; ++ii) s += ldf(Wself, ii * 3 + o, isb) * v[l * 9 + ii * 3 + xx];
    soff[lane] = s;
  }
  __syncthreads();
  if (lane < 9) {
    int xx = lane % 3;
    float add = (l == 0) ? 0.f : (CA[l * 3 + xx] + soff[3 + xx]);  // residue 0 zeroed
    stf(out, l * 9 + lane, soff[lane] + add, isb);
  }
}

extern "C" void kernel_launch(void* const* d_in, const int* in_sizes, int n_in,
                              void* d_out, int out_size, void* d_ws, size_t ws_size,
                              hipStream_t stream) {
  (void)in_sizes; (void)n_in; (void)out_size; (void)ws_size;
  const void* xyz     = d_in[0];
  const void* state   = d_in[1];
  const void* msa     = d_in[4];
  const void* pair    = d_in[5];
  const void* seq1hot = d_in[6];
  const void* g_msa   = d_in[10];
  const void* b_msa   = d_in[11];
  const void* g_pair  = d_in[12];
  const void* b_pair  = d_in[13];
  const void* g_state = d_in[14];
  const void* b_state = d_in[15];
  const void* g_node  = d_in[16];
  const void* b_node  = d_in[17];
  const void* g_e1    = d_in[18];
  const void* b_e1    = d_in[19];
  const void* Wx      = d_in[20];
  const void* bx      = d_in[21];
  const void* We1     = d_in[22];
  const void* be1     = d_in[23];
  const void* W1      = d_in[24];
  const void* b1      = d_in[25];
  const void* W2      = d_in[26];
  const void* b2      = d_in[27];
  const void* Wv      = d_in[28];
  const void* Wvv     = d_in[29];
  const void* Wself   = d_in[30];
  const void* Wl      = d_in[31];
  const void* bl      = d_in[32];

  float* ws    = (float*)d_ws;
  float* l0    = ws;            // 512*32
  float* CA    = ws + 16384;    // 512*3
  float* v     = ws + 17920;    // 512*9
  float* vproj = ws + 22528;    // 512*9
  float* agg   = ws + 27136;    // 512*32
  float* v_agg = ws + 43520;    // 512*9
  int*   nbr   = (int*)(ws + 48128);  // 512*64 ints
  int*   dflag = (int*)(ws + 80896);

  hipLaunchKernelGGL(k_detect, dim3(1), dim3(64), 0, stream,
                     (const unsigned int*)g_msa, dflag);
  hipLaunchKernelGGL(k_node, dim3(512), dim3(256), 0, stream,
                     xyz, state, msa, seq1hot, g_msa, b_msa, g_state, b_state,
                     g_node, b_node, Wx, bx, Wvv, dflag, l0, CA, v, vproj, agg, v_agg);
  hipLaunchKernelGGL(k_topk, dim3(512), dim3(256), 0, stream, CA, nbr);
  hipLaunchKernelGGL(k_edge, dim3(1024), dim3(256), 0, stream,
                     pair, g_pair, b_pair, We1, be1, g_e1, b_e1, W1, b1, Wv, dflag,
                     nbr, l0, CA, v, vproj, agg, v_agg);
  hipLaunchKernelGGL(k_out, dim3(512), dim3(64), 0, stream,
                     l0, agg, v, v_agg, CA, W2, b2, Wself, g_state, b_state, Wl, bl,
                     dflag, (void*)d_out);
}